// Round 7
// baseline (320.289 us; speedup 1.0000x reference)
//
#include <hip/hip_runtime.h>
#include <math.h>

// SGC: out = log_softmax( S^3 * x * (W1*W2*W3) )
// Pipeline: fused weight collapse -> dense GEMM (f32 in, bf16 out, 128B rows)
// -> strided bucket partition (no pre-scan) -> bucket-local CSR (beg/end)
// -> 3x wave-per-node packed gather-agg with preloaded src indices.
// NOTE: all __shfl distributing src indices are executed UNCONDITIONALLY by
// all 64 lanes (divergent shfl with inactive provider lanes is undefined).

#define BW    128     // nodes per bucket
#define NBMAX 1024
#define BCAP  3072    // per-bucket capacity (avg 2048, +22 sigma slack)
#define D     40
#define RS    64      // padded row stride (bf16 elems) = 128 B

typedef unsigned short u16;
typedef unsigned int   u32;

static __device__ inline u16 f2bf(float f) {
    u32 u = __float_as_uint(f);
    u32 r = (u + 0x7FFF + ((u >> 16) & 1)) >> 16;
    return (u16)r;
}
static __device__ inline u32 pack2(float lo, float hi) {
    return (u32)f2bf(lo) | ((u32)f2bf(hi) << 16);
}

// ---------- fused weight collapse: Wc = (W1 @ W2) @ W3, one block ----------
__global__ void k_wfuse(const float* __restrict__ W1, const float* __restrict__ W2,
                        const float* __restrict__ W3, float* __restrict__ Wc) {
    __shared__ float w12[128 * 64];
    int t = threadIdx.x;                       // 256 threads
    for (int i = t; i < 128 * 64; i += 256) {
        int r = i >> 6, c = i & 63;
        float acc = 0.f;
#pragma unroll
        for (int k = 0; k < 64; ++k) acc += W1[r * 64 + k] * W2[k * 64 + c];
        w12[i] = acc;
    }
    __syncthreads();
    for (int i = t; i < 128 * 40; i += 256) {
        int r = i / 40, c = i - r * 40;
        float acc = 0.f;
#pragma unroll
        for (int k = 0; k < 64; ++k) acc += w12[r * 64 + k] * W3[k * 40 + c];
        Wc[i] = acc;
    }
}

// ---------- y0 = x(N x 128) @ Wc(128x40), bf16 out, row stride RS ----------
__global__ void k_gemm(const float4* __restrict__ x4, const float4* __restrict__ Wc4,
                       u16* __restrict__ yout, int n_nodes) {
    __shared__ float4 wc[128 * 10];
    for (int i = threadIdx.x; i < 1280; i += blockDim.x) wc[i] = Wc4[i];
    __syncthreads();
    int tid = blockIdx.x * blockDim.x + threadIdx.x;
    int node = tid / 5, j0 = tid - node * 5;
    if (node >= n_nodes) return;
    float4 a0 = {0.f, 0.f, 0.f, 0.f}, a1 = {0.f, 0.f, 0.f, 0.f};
    const float4* xr = x4 + (size_t)node * 32;
#pragma unroll
    for (int k4 = 0; k4 < 32; ++k4) {
        float4 v = xr[k4];
#pragma unroll
        for (int kk = 0; kk < 4; ++kk) {
            float c = (kk == 0) ? v.x : (kk == 1) ? v.y : (kk == 2) ? v.z : v.w;
            float4 w0 = wc[(k4 * 4 + kk) * 10 + j0 * 2];
            float4 w1 = wc[(k4 * 4 + kk) * 10 + j0 * 2 + 1];
            a0.x += c * w0.x; a0.y += c * w0.y; a0.z += c * w0.z; a0.w += c * w0.w;
            a1.x += c * w1.x; a1.y += c * w1.y; a1.z += c * w1.z; a1.w += c * w1.w;
        }
    }
    uint4 st;
    st.x = pack2(a0.x, a0.y); st.y = pack2(a0.z, a0.w);
    st.z = pack2(a1.x, a1.y); st.w = pack2(a1.z, a1.w);
    *(uint4*)(yout + (size_t)node * RS + j0 * 8) = st;
}

// ---------- partition edges into strided buckets (no pre-scan) ----------
// bucket b owns part[b*BCAP .. b*BCAP+cnt); packed (src<<7)|(dst&127)
#define PCHUNK 8192
__global__ void k_part(const int* __restrict__ src, const int* __restrict__ dst,
                       int* __restrict__ gcnt, int* __restrict__ part,
                       int E, int nb) {
    __shared__ int h[NBMAX];
    __shared__ int base[NBMAX];
    int t = threadIdx.x;
    int e0 = blockIdx.x * PCHUNK;
    int e1 = min(e0 + PCHUNK, E);
    for (int i = t; i < nb; i += 256) h[i] = 0;
    __syncthreads();
    for (int e = e0 + t; e < e1; e += 256)
        atomicAdd(&h[dst[e] >> 7], 1);
    __syncthreads();
    for (int i = t; i < nb; i += 256) {
        int c = h[i];
        base[i] = c ? atomicAdd(&gcnt[i], c) : 0;
    }
    __syncthreads();
    for (int i = t; i < nb; i += 256) h[i] = 0;   // reuse as local cursor
    __syncthreads();
    for (int e = e0 + t; e < e1; e += 256) {
        int d = dst[e];
        int b = d >> 7;
        int p = base[b] + atomicAdd(&h[b], 1);
        if (p < BCAP) part[(size_t)b * BCAP + p] = (src[e] << 7) | (d & 127);
    }
}

// ---------- bucket-local CSR: beg[n], end[n], ssort (src grouped by dst) ----
__global__ void k_csr(const int* __restrict__ part, const int* __restrict__ gcnt,
                      int* __restrict__ begv, int* __restrict__ endv,
                      int* __restrict__ ssort, int N) {
    __shared__ int cnt[BW];
    __shared__ int pos[BW];
    __shared__ int cur[BW];
    __shared__ int wsum[2];
    int b = blockIdx.x, t = threadIdx.x;
    int m = min(gcnt[b], BCAP);
    const int* bp = part + (size_t)b * BCAP;
    if (t < BW) cnt[t] = 0;
    __syncthreads();
    for (int k = t; k < m; k += 256)
        atomicAdd(&cnt[bp[k] & 127], 1);
    __syncthreads();
    int v = 0, inc = 0;
    if (t < BW) {
        v = cnt[t];
        inc = v;
#pragma unroll
        for (int off = 1; off < 64; off <<= 1) {
            int u = __shfl_up(inc, off, 64);
            if ((t & 63) >= off) inc += u;
        }
        if ((t & 63) == 63) wsum[t >> 6] = inc;
    }
    __syncthreads();
    int node0 = b * BW;
    if (t < BW) {
        int local = ((t >= 64) ? wsum[0] : 0) + inc - v;   // exclusive
        pos[t] = local;
        cur[t] = 0;
        if (node0 + t < N) {
            begv[node0 + t] = b * BCAP + local;
            endv[node0 + t] = b * BCAP + local + v;
        }
    }
    __syncthreads();
    for (int k = t; k < m; k += 256) {
        int p = bp[k];
        int r = p & 127;
        int loc = atomicAdd(&cur[r], 1);
        ssort[(size_t)b * BCAP + pos[r] + loc] = p >> 7;
    }
}

// ---------- aggregation: wave per node, packed gather, preloaded srcs ------
// 6 groups of 10 lanes; group g handles edges k+g+6j; lane loads uint2
// (4 bf16). src indices preloaded (one coalesced load, deg<=64) and
// distributed via UNCONDITIONAL shfl -> 4 independent gathers in flight.
template <int FINAL>
__global__ void k_agg(const u16* __restrict__ yin, void* __restrict__ youtv,
                      const int* __restrict__ begv, const int* __restrict__ endv,
                      const int* __restrict__ srcs, int n_nodes) {
    int wid = (blockIdx.x * blockDim.x + threadIdx.x) >> 6;
    int lane = threadIdx.x & 63;
    if (wid >= n_nodes) return;
    int beg = begv[wid];
    int deg = endv[wid] - beg;
    int g = lane / 10;            // 0..6 (lanes 60..63 idle for gather)
    int sub = lane - g * 10;      // 0..9
    bool act = (g < 6);
    const char* base = (const char*)yin + sub * 8;
    int sv = (lane < deg) ? srcs[beg + lane] : 0;
    float a0 = 0.f, a1 = 0.f, a2 = 0.f, a3 = 0.f;
    int dlim = min(deg, 64);
    for (int k = 0; k < dlim; k += 24) {
#pragma unroll
        for (int j = 0; j < 4; ++j) {
            int e = k + g + 6 * j;
            int es = (e < dlim) ? e : 0;
            int s = __shfl(sv, es, 64);          // ALL lanes execute
            if (act && e < dlim) {
                uint2 w = *(const uint2*)(base + (size_t)((u32)s * 128u));
                a0 += __uint_as_float(w.x << 16);
                a1 += __uint_as_float(w.x & 0xFFFF0000u);
                a2 += __uint_as_float(w.y << 16);
                a3 += __uint_as_float(w.y & 0xFFFF0000u);
            }
        }
    }
    // rare tail: deg > 64 (direct loads, no shfl)
    for (int k = 64 + g; k < deg; k += 6) {
        if (act) {
            uint2 w = *(const uint2*)(base + (size_t)((u32)srcs[beg + k] * 128u));
            a0 += __uint_as_float(w.x << 16);
            a1 += __uint_as_float(w.x & 0xFFFF0000u);
            a2 += __uint_as_float(w.y << 16);
            a3 += __uint_as_float(w.y & 0xFFFF0000u);
        }
    }
    // fold 6 groups -> lanes 0..9
    float b0 = a0 + __shfl(a0, lane + 30, 64);
    float b1 = a1 + __shfl(a1, lane + 30, 64);
    float b2 = a2 + __shfl(a2, lane + 30, 64);
    float b3 = a3 + __shfl(a3, lane + 30, 64);
    float s0 = b0 + __shfl(b0, lane + 10, 64) + __shfl(b0, lane + 20, 64);
    float s1 = b1 + __shfl(b1, lane + 10, 64) + __shfl(b1, lane + 20, 64);
    float s2 = b2 + __shfl(b2, lane + 10, 64) + __shfl(b2, lane + 20, 64);
    float s3 = b3 + __shfl(b3, lane + 10, 64) + __shfl(b3, lane + 20, 64);
    if (FINAL) {
        float m = fmaxf(fmaxf(s0, s1), fmaxf(s2, s3));
        float mv = (lane < 10) ? m : -INFINITY;
#pragma unroll
        for (int off = 8; off; off >>= 1) mv = fmaxf(mv, __shfl_xor(mv, off, 16));
        float ev = 0.f;
        if (lane < 10)
            ev = __expf(s0 - mv) + __expf(s1 - mv) + __expf(s2 - mv) + __expf(s3 - mv);
#pragma unroll
        for (int off = 8; off; off >>= 1) ev += __shfl_xor(ev, off, 16);
        float ls = __logf(ev);
        if (lane < 10) {
            float4 o = {s0 - mv - ls, s1 - mv - ls, s2 - mv - ls, s3 - mv - ls};
            ((float4*)((float*)youtv + (size_t)wid * D))[sub] = o;
        }
    } else {
        if (lane < 10) {
            uint2 st = {pack2(s0, s1), pack2(s2, s3)};
            *(uint2*)((u16*)youtv + (size_t)wid * RS + sub * 4) = st;
        }
    }
}

extern "C" void kernel_launch(void* const* d_in, const int* in_sizes, int n_in,
                              void* d_out, int out_size, void* d_ws, size_t ws_size,
                              hipStream_t stream) {
    const float* x   = (const float*)d_in[0];
    const int* esrc  = (const int*)d_in[1];
    const int* edst  = (const int*)d_in[2];
    const float* W1  = (const float*)d_in[3];
    const float* W2  = (const float*)d_in[4];
    const float* W3  = (const float*)d_in[5];
    int N = in_sizes[0] / 128;
    int E = in_sizes[1];
    float* out = (float*)d_out;

    int nb = (N + BW - 1) / BW;

    char* ws = (char*)d_ws;
    auto alloc = [&](size_t bytes) {
        char* p = ws;
        ws += (bytes + 255) & ~(size_t)255;
        return p;
    };
    u16* bufA   = (u16*)alloc((size_t)N * RS * sizeof(u16));        // 12.8 MB
    u16* bufB   = (u16*)alloc((size_t)N * RS * sizeof(u16));        // 12.8 MB
    int* part   = (int*)bufB;   // alias: part dead before bufB first written
    int* ssort  = (int*)alloc((size_t)nb * BCAP * sizeof(int));     // 9.6 MB
    int* begv   = (int*)alloc((size_t)N * sizeof(int));
    int* endv   = (int*)alloc((size_t)N * sizeof(int));
    float* Wc   = (float*)alloc(128 * 40 * sizeof(float));
    int* gcnt   = (int*)alloc(NBMAX * sizeof(int));

    hipMemsetAsync(gcnt, 0, NBMAX * sizeof(int), stream);

    k_wfuse<<<1, 256, 0, stream>>>(W1, W2, W3, Wc);
    k_gemm<<<(N * 5 + 255) / 256, 256, 0, stream>>>((const float4*)x, (const float4*)Wc,
                                                    bufA, N);

    k_part<<<(E + PCHUNK - 1) / PCHUNK, 256, 0, stream>>>(esrc, edst, gcnt, part, E, nb);
    k_csr<<<nb, 256, 0, stream>>>(part, gcnt, begv, endv, ssort, N);

    int agg_grid = (N * 64 + 255) / 256;
    k_agg<0><<<agg_grid, 256, 0, stream>>>(bufA, bufB, begv, endv, ssort, N);
    k_agg<0><<<agg_grid, 256, 0, stream>>>(bufB, bufA, begv, endv, ssort, N);
    k_agg<1><<<agg_grid, 256, 0, stream>>>(bufA, out, begv, endv, ssort, N);
}

// Round 8
// 201.219 us; speedup vs baseline: 1.5917x; 1.5917x over previous
//
#include <hip/hip_runtime.h>
#include <math.h>

// SGC: out = log_softmax( S^3 * x * (W1*W2*W3) )
// Pipeline: weight collapse (2 multi-block kernels) -> dense GEMM (f32 in,
// bf16 out, 128B rows) -> strided bucket partition (no pre-scan) ->
// bucket-local CSR (beg/end) -> 3x wave-per-node packed gather-agg.
// NOTE: all __shfl distributing src indices are executed UNCONDITIONALLY by
// all 64 lanes (divergent shfl with inactive provider lanes is undefined).

#define BW    128     // nodes per bucket
#define NBMAX 1024
#define BCAP  3072    // per-bucket capacity (avg 2048, +22 sigma slack)
#define D     40
#define RS    64      // padded row stride (bf16 elems) = 128 B

typedef unsigned short u16;
typedef unsigned int   u32;

static __device__ inline u16 f2bf(float f) {
    u32 u = __float_as_uint(f);
    u32 r = (u + 0x7FFF + ((u >> 16) & 1)) >> 16;
    return (u16)r;
}
static __device__ inline u32 pack2(float lo, float hi) {
    return (u32)f2bf(lo) | ((u32)f2bf(hi) << 16);
}

// ---------- weight collapse, multi-block (occupancy!) ----------
// W12 = W1(128x64) @ W2(64x64); block 0 also zeroes gcnt
__global__ void k_w12(const float* __restrict__ W1, const float* __restrict__ W2,
                      float* __restrict__ W12, int* __restrict__ gcnt) {
    int idx = blockIdx.x * blockDim.x + threadIdx.x;
    if (blockIdx.x == 0) {
        for (int i = threadIdx.x; i < NBMAX; i += blockDim.x) gcnt[i] = 0;
    }
    if (idx >= 128 * 64) return;
    int r = idx >> 6, c = idx & 63;
    float acc = 0.f;
#pragma unroll
    for (int k = 0; k < 64; ++k) acc += W1[r * 64 + k] * W2[k * 64 + c];
    W12[idx] = acc;
}

// Wc = W12(128x64) @ W3(64x40)
__global__ void k_wc(const float* __restrict__ W12, const float* __restrict__ W3,
                     float* __restrict__ Wc) {
    int idx = blockIdx.x * blockDim.x + threadIdx.x;
    if (idx >= 128 * 40) return;
    int r = idx / 40, c = idx - r * 40;
    float acc = 0.f;
#pragma unroll
    for (int k = 0; k < 64; ++k) acc += W12[r * 64 + k] * W3[k * 40 + c];
    Wc[idx] = acc;
}

// ---------- y0 = x(N x 128) @ Wc(128x40), bf16 out, row stride RS ----------
__global__ void k_gemm(const float4* __restrict__ x4, const float4* __restrict__ Wc4,
                       u16* __restrict__ yout, int n_nodes) {
    __shared__ float4 wc[128 * 10];
    for (int i = threadIdx.x; i < 1280; i += blockDim.x) wc[i] = Wc4[i];
    __syncthreads();
    int tid = blockIdx.x * blockDim.x + threadIdx.x;
    int node = tid / 5, j0 = tid - node * 5;
    if (node >= n_nodes) return;
    float4 a0 = {0.f, 0.f, 0.f, 0.f}, a1 = {0.f, 0.f, 0.f, 0.f};
    const float4* xr = x4 + (size_t)node * 32;
#pragma unroll
    for (int k4 = 0; k4 < 32; ++k4) {
        float4 v = xr[k4];
#pragma unroll
        for (int kk = 0; kk < 4; ++kk) {
            float c = (kk == 0) ? v.x : (kk == 1) ? v.y : (kk == 2) ? v.z : v.w;
            float4 w0 = wc[(k4 * 4 + kk) * 10 + j0 * 2];
            float4 w1 = wc[(k4 * 4 + kk) * 10 + j0 * 2 + 1];
            a0.x += c * w0.x; a0.y += c * w0.y; a0.z += c * w0.z; a0.w += c * w0.w;
            a1.x += c * w1.x; a1.y += c * w1.y; a1.z += c * w1.z; a1.w += c * w1.w;
        }
    }
    uint4 st;
    st.x = pack2(a0.x, a0.y); st.y = pack2(a0.z, a0.w);
    st.z = pack2(a1.x, a1.y); st.w = pack2(a1.z, a1.w);
    *(uint4*)(yout + (size_t)node * RS + j0 * 8) = st;
}

// ---------- partition edges into strided buckets (no pre-scan) ----------
// bucket b owns part[b*BCAP .. b*BCAP+cnt); packed (src<<7)|(dst&127)
#define PCHUNK 8192
__global__ void k_part(const int* __restrict__ src, const int* __restrict__ dst,
                       int* __restrict__ gcnt, int* __restrict__ part,
                       int E, int nb) {
    __shared__ int h[NBMAX];
    __shared__ int base[NBMAX];
    int t = threadIdx.x;
    int e0 = blockIdx.x * PCHUNK;
    int e1 = min(e0 + PCHUNK, E);
    for (int i = t; i < nb; i += 256) h[i] = 0;
    __syncthreads();
    for (int e = e0 + t; e < e1; e += 256)
        atomicAdd(&h[dst[e] >> 7], 1);
    __syncthreads();
    for (int i = t; i < nb; i += 256) {
        int c = h[i];
        base[i] = c ? atomicAdd(&gcnt[i], c) : 0;
    }
    __syncthreads();
    for (int i = t; i < nb; i += 256) h[i] = 0;   // reuse as local cursor
    __syncthreads();
    for (int e = e0 + t; e < e1; e += 256) {
        int d = dst[e];
        int b = d >> 7;
        int p = base[b] + atomicAdd(&h[b], 1);
        if (p < BCAP) part[(size_t)b * BCAP + p] = (src[e] << 7) | (d & 127);
    }
}

// ---------- bucket-local CSR: beg[n], end[n], ssort (src grouped by dst) ----
__global__ void k_csr(const int* __restrict__ part, const int* __restrict__ gcnt,
                      int* __restrict__ begv, int* __restrict__ endv,
                      int* __restrict__ ssort, int N) {
    __shared__ int cnt[BW];
    __shared__ int pos[BW];
    __shared__ int cur[BW];
    __shared__ int wsum[2];
    int b = blockIdx.x, t = threadIdx.x;
    int m = min(gcnt[b], BCAP);
    const int* bp = part + (size_t)b * BCAP;
    if (t < BW) cnt[t] = 0;
    __syncthreads();
    for (int k = t; k < m; k += 256)
        atomicAdd(&cnt[bp[k] & 127], 1);
    __syncthreads();
    int v = 0, inc = 0;
    if (t < BW) {
        v = cnt[t];
        inc = v;
#pragma unroll
        for (int off = 1; off < 64; off <<= 1) {
            int u = __shfl_up(inc, off, 64);
            if ((t & 63) >= off) inc += u;
        }
        if ((t & 63) == 63) wsum[t >> 6] = inc;
    }
    __syncthreads();
    int node0 = b * BW;
    if (t < BW) {
        int local = ((t >= 64) ? wsum[0] : 0) + inc - v;   // exclusive
        pos[t] = local;
        cur[t] = 0;
        if (node0 + t < N) {
            begv[node0 + t] = b * BCAP + local;
            endv[node0 + t] = b * BCAP + local + v;
        }
    }
    __syncthreads();
    for (int k = t; k < m; k += 256) {
        int p = bp[k];
        int r = p & 127;
        int loc = atomicAdd(&cur[r], 1);
        ssort[(size_t)b * BCAP + pos[r] + loc] = p >> 7;
    }
}

// ---------- aggregation: wave per node, packed gather, preloaded srcs ------
// 6 groups of 10 lanes; group g handles edges k+g+6j; lane loads uint2
// (4 bf16). src indices preloaded (one coalesced load, deg<=64) and
// distributed via UNCONDITIONAL shfl -> 4 independent gathers in flight.
template <int FINAL>
__global__ void k_agg(const u16* __restrict__ yin, void* __restrict__ youtv,
                      const int* __restrict__ begv, const int* __restrict__ endv,
                      const int* __restrict__ srcs, int n_nodes) {
    int wid = (blockIdx.x * blockDim.x + threadIdx.x) >> 6;
    int lane = threadIdx.x & 63;
    if (wid >= n_nodes) return;
    int beg = begv[wid];
    int deg = endv[wid] - beg;
    int g = lane / 10;            // 0..6 (lanes 60..63 idle for gather)
    int sub = lane - g * 10;      // 0..9
    bool act = (g < 6);
    const char* base = (const char*)yin + sub * 8;
    int sv = (lane < deg) ? srcs[beg + lane] : 0;
    float a0 = 0.f, a1 = 0.f, a2 = 0.f, a3 = 0.f;
    int dlim = min(deg, 64);
    for (int k = 0; k < dlim; k += 24) {
#pragma unroll
        for (int j = 0; j < 4; ++j) {
            int e = k + g + 6 * j;
            int es = (e < dlim) ? e : 0;
            int s = __shfl(sv, es, 64);          // ALL lanes execute
            if (act && e < dlim) {
                uint2 w = *(const uint2*)(base + (size_t)((u32)s * 128u));
                a0 += __uint_as_float(w.x << 16);
                a1 += __uint_as_float(w.x & 0xFFFF0000u);
                a2 += __uint_as_float(w.y << 16);
                a3 += __uint_as_float(w.y & 0xFFFF0000u);
            }
        }
    }
    // rare tail: deg > 64 (direct loads, no shfl)
    for (int k = 64 + g; k < deg; k += 6) {
        if (act) {
            uint2 w = *(const uint2*)(base + (size_t)((u32)srcs[beg + k] * 128u));
            a0 += __uint_as_float(w.x << 16);
            a1 += __uint_as_float(w.x & 0xFFFF0000u);
            a2 += __uint_as_float(w.y << 16);
            a3 += __uint_as_float(w.y & 0xFFFF0000u);
        }
    }
    // fold 6 groups -> lanes 0..9
    float b0 = a0 + __shfl(a0, lane + 30, 64);
    float b1 = a1 + __shfl(a1, lane + 30, 64);
    float b2 = a2 + __shfl(a2, lane + 30, 64);
    float b3 = a3 + __shfl(a3, lane + 30, 64);
    float s0 = b0 + __shfl(b0, lane + 10, 64) + __shfl(b0, lane + 20, 64);
    float s1 = b1 + __shfl(b1, lane + 10, 64) + __shfl(b1, lane + 20, 64);
    float s2 = b2 + __shfl(b2, lane + 10, 64) + __shfl(b2, lane + 20, 64);
    float s3 = b3 + __shfl(b3, lane + 10, 64) + __shfl(b3, lane + 20, 64);
    if (FINAL) {
        float m = fmaxf(fmaxf(s0, s1), fmaxf(s2, s3));
        float mv = (lane < 10) ? m : -INFINITY;
#pragma unroll
        for (int off = 8; off; off >>= 1) mv = fmaxf(mv, __shfl_xor(mv, off, 16));
        float ev = 0.f;
        if (lane < 10)
            ev = __expf(s0 - mv) + __expf(s1 - mv) + __expf(s2 - mv) + __expf(s3 - mv);
#pragma unroll
        for (int off = 8; off; off >>= 1) ev += __shfl_xor(ev, off, 16);
        float ls = __logf(ev);
        if (lane < 10) {
            float4 o = {s0 - mv - ls, s1 - mv - ls, s2 - mv - ls, s3 - mv - ls};
            ((float4*)((float*)youtv + (size_t)wid * D))[sub] = o;
        }
    } else {
        if (lane < 10) {
            uint2 st = {pack2(s0, s1), pack2(s2, s3)};
            *(uint2*)((u16*)youtv + (size_t)wid * RS + sub * 4) = st;
        }
    }
}

extern "C" void kernel_launch(void* const* d_in, const int* in_sizes, int n_in,
                              void* d_out, int out_size, void* d_ws, size_t ws_size,
                              hipStream_t stream) {
    const float* x   = (const float*)d_in[0];
    const int* esrc  = (const int*)d_in[1];
    const int* edst  = (const int*)d_in[2];
    const float* W1  = (const float*)d_in[3];
    const float* W2  = (const float*)d_in[4];
    const float* W3  = (const float*)d_in[5];
    int N = in_sizes[0] / 128;
    int E = in_sizes[1];
    float* out = (float*)d_out;

    int nb = (N + BW - 1) / BW;

    char* ws = (char*)d_ws;
    auto alloc = [&](size_t bytes) {
        char* p = ws;
        ws += (bytes + 255) & ~(size_t)255;
        return p;
    };
    u16* bufA   = (u16*)alloc((size_t)N * RS * sizeof(u16));        // 12.8 MB
    u16* bufB   = (u16*)alloc((size_t)N * RS * sizeof(u16));        // 12.8 MB
    int* part   = (int*)bufB;   // alias: part dead before bufB first written
    int* ssort  = (int*)alloc((size_t)nb * BCAP * sizeof(int));     // 9.6 MB
    int* begv   = (int*)alloc((size_t)N * sizeof(int));
    int* endv   = (int*)alloc((size_t)N * sizeof(int));
    float* W12  = (float*)alloc(128 * 64 * sizeof(float));
    float* Wc   = (float*)alloc(128 * 40 * sizeof(float));
    int* gcnt   = (int*)alloc(NBMAX * sizeof(int));

    k_w12<<<(128 * 64 + 255) / 256, 256, 0, stream>>>(W1, W2, W12, gcnt);
    k_wc<<<(128 * 40 + 255) / 256, 256, 0, stream>>>(W12, W3, Wc);
    k_gemm<<<(N * 5 + 255) / 256, 256, 0, stream>>>((const float4*)x, (const float4*)Wc,
                                                    bufA, N);

    k_part<<<(E + PCHUNK - 1) / PCHUNK, 256, 0, stream>>>(esrc, edst, gcnt, part, E, nb);
    k_csr<<<nb, 256, 0, stream>>>(part, gcnt, begv, endv, ssort, N);

    int agg_grid = (N * 64 + 255) / 256;
    k_agg<0><<<agg_grid, 256, 0, stream>>>(bufA, bufB, begv, endv, ssort, N);
    k_agg<0><<<agg_grid, 256, 0, stream>>>(bufB, bufA, begv, endv, ssort, N);
    k_agg<1><<<agg_grid, 256, 0, stream>>>(bufA, out, begv, endv, ssort, N);
}